// Round 1
// baseline (287.146 us; speedup 1.0000x reference)
//
#include <hip/hip_runtime.h>

#define NCONDS 50
#define EMB 64
#define ROW_STRIDE (1 + NCONDS)          // 51 indices per row
#define OUT_STRIDE ((1 + NCONDS) * EMB)  // 3264 floats per row
#define NSLICE 8                          // one table slice per XCD
#define SLICE_ROWS 12501u                 // ceil(100002/8) -> slices 0..7, ~3.2MB each (fits 4MB L2)
#define ROWS_PER_BLOCK 64
#define ROWS_PER_WAVE 16

typedef float f4 __attribute__((ext_vector_type(4)));

// 16-lane-row sum reduction on the VALU via DPP row_ror (no DS pipe).
template<int CTRL>
__device__ __forceinline__ float dpp_add(float x) {
    int y = __builtin_amdgcn_update_dpp(0, __builtin_bit_cast(int, x),
                                        CTRL, 0xf, 0xf, true);
    return x + __builtin_bit_cast(float, y);
}
__device__ __forceinline__ float reduce16(float x) {
    x = dpp_add<0x121>(x);   // ror 1
    x = dpp_add<0x122>(x);   // ror 2
    x = dpp_add<0x124>(x);   // ror 4
    x = dpp_add<0x128>(x);   // ror 8
    return x;
}

__device__ __forceinline__ int slice_of(int idx) {
    return (int)((unsigned)idx / SLICE_ROWS);   // magic-mul, contiguous ranges (L2-set friendly)
}

// Slice-partitioned gather kernel:
//   blockIdx % 8  -> table slice (round-robins onto XCD 0..7, so each XCD's L2
//                    only caches its own ~3.2MB contiguous slice of the table)
//   blockIdx / 8  -> 64-row batch chunk; 4 waves x 16 rows each.
// Per row: full wave scans the 50 condition indices, keeps those in its slice
// (ballot + prefix-popcount compaction into LDS), then processes 4 at a time
// in 16-lane groups exactly like the baseline (identical math/rounding).
__global__ __launch_bounds__(256) void cond_filter_sliced(
    const int*   __restrict__ inp,     // (B, 51) int32
    const float* __restrict__ table,   // (100002, 64) fp32
    float*       __restrict__ out,     // (B, 3264) fp32
    int batch)
{
    __shared__ int cl[4][64];          // per-wave compacted (idx<<6 | c) list

    const int wv   = threadIdx.x >> 6;            // wave in block 0..3
    const int lane = threadIdx.x & 63;
    const int grp  = lane >> 4;                   // 16-lane group 0..3
    const int gl   = lane & 15;                   // lane within group

    const int slice  = blockIdx.x & (NSLICE - 1);
    const int rowblk = blockIdx.x >> 3;
    int rbase = rowblk * ROWS_PER_BLOCK + wv * ROWS_PER_WAVE;
    rbase = __builtin_amdgcn_readfirstlane(rbase);

    if (rbase >= batch) return;

    // Pipelined index fetch for the wave's first row.
    const int* row0 = inp + (size_t)rbase * ROW_STRIDE;
    int e_idx = row0[0];                                               // uniform -> s_load
    int ci = (lane < NCONDS) ? __builtin_nontemporal_load(row0 + 1 + lane) : 0;

    for (int rr = 0; rr < ROWS_PER_WAVE; ++rr) {
        const int b = rbase + rr;
        if (b >= batch) return;

        // Prefetch next row's indices (breaks the per-row latency chain).
        int e_nx = 0, ci_nx = 0;
        if (rr + 1 < ROWS_PER_WAVE && b + 1 < batch) {
            const int* nrow = inp + (size_t)(b + 1) * ROW_STRIDE;
            e_nx  = nrow[0];
            ci_nx = (lane < NCONDS) ? __builtin_nontemporal_load(nrow + 1 + lane) : 0;
        }

        float* orow = out + (size_t)b * OUT_STRIDE;

        // Event embedding + normalization (replicated across slices; nt-load so
        // out-of-slice event rows don't evict this XCD's resident table slice).
        const f4 ev = __builtin_nontemporal_load(
            (const f4*)(table + (size_t)e_idx * EMB + gl * 4));
        const float es = reduce16(ev.x*ev.x + ev.y*ev.y + ev.z*ev.z + ev.w*ev.w);
        const f4 en = ev * rsqrtf(es);

        // Raw event output written exactly once: by the slice owning e_idx.
        if ((slice_of(e_idx) == slice) && grp == 0)
            __builtin_nontemporal_store(ev, (f4*)(orow + gl * 4));

        // Conditions owned by this slice: ballot + compact into LDS.
        const bool match = (lane < NCONDS) && (slice_of(ci) == slice);
        const unsigned long long m = __ballot(match);
        const int cnt = __popcll(m);

        if (cnt > 0) {
            if (match) {
                const int pos = __popcll(m & ((1ull << lane) - 1));
                cl[wv][pos] = (ci << 6) | lane;    // idx<=100001 (17b) <<6 | c (6b)
            }
            const int nt = (cnt + 3) >> 2;         // 4 conditions per pass (one per group)
            for (int t = 0; t < nt; ++t) {
                const int e  = t * 4 + grp;
                const int pk = cl[wv][e < cnt ? e : cnt - 1];  // clamp keeps inactive groups safe
                const int c   = pk & 63;
                const int idx = pk >> 6;
                // In-slice gather: L2-resident after first touch.
                const f4 v = *(const f4*)(table + (size_t)idx * EMB + gl * 4);
                const float cs = reduce16(v.x*v.x + v.y*v.y + v.z*v.z + v.w*v.w);
                const float dp = reduce16(v.x*en.x + v.y*en.y + v.z*en.z + v.w*en.w);
                // filtered = (v/|v|) * dot(en, v/|v|) = v * dp / cs  (same as baseline)
                const float scale = dp * __builtin_amdgcn_rcpf(cs);
                if (e < cnt) {
                    const f4 o = v * scale;
                    __builtin_nontemporal_store(o,
                        (f4*)(orow + EMB + (size_t)c * EMB + gl * 4));
                }
            }
        }

        e_idx = e_nx;
        ci    = ci_nx;
    }
}

extern "C" void kernel_launch(void* const* d_in, const int* in_sizes, int n_in,
                              void* d_out, int out_size, void* d_ws, size_t ws_size,
                              hipStream_t stream) {
    const int*   inp   = (const int*)d_in[0];
    const float* table = (const float*)d_in[1];
    float*       out   = (float*)d_out;

    const int batch   = in_sizes[0] / ROW_STRIDE;                    // 16384
    const int rowblks = (batch + ROWS_PER_BLOCK - 1) / ROWS_PER_BLOCK;
    const int blocks  = rowblks * NSLICE;                            // 2048

    hipLaunchKernelGGL(cond_filter_sliced, dim3(blocks), dim3(256), 0, stream,
                       inp, table, out, batch);
}

// Round 2
// 252.562 us; speedup vs baseline: 1.1369x; 1.1369x over previous
//
#include <hip/hip_runtime.h>

#define NCONDS 50
#define EMB 64
#define ROW_STRIDE (1 + NCONDS)          // 51 indices per row
#define OUT_STRIDE ((1 + NCONDS) * EMB)  // 3264 floats per row
#define NITER 13                         // ceil(50/4) condition iterations
#define TABLE_ROWS 100002

typedef float f4 __attribute__((ext_vector_type(4)));

// 16-lane-row sum reduction on the VALU via DPP row_ror (no DS pipe, no lgkmcnt).
template<int CTRL>
__device__ __forceinline__ float dpp_add(float x) {
    int y = __builtin_amdgcn_update_dpp(0, __builtin_bit_cast(int, x),
                                        CTRL, 0xf, 0xf, true);
    return x + __builtin_bit_cast(float, y);
}
__device__ __forceinline__ float reduce16(float x) {
    x = dpp_add<0x121>(x);   // ror 1
    x = dpp_add<0x122>(x);   // ror 2
    x = dpp_add<0x124>(x);   // ror 4
    x = dpp_add<0x128>(x);   // ror 8
    return x;                // every lane holds the 16-lane sum
}

// One wave per batch row; 4 groups of 16 lanes; lane holds f4 (4 of 64 dims).
// Indices via scalar loads (wave-uniform row), reductions via DPP -> zero DS ops.
// NEW vs best-known: cooperative streaming L3-warm of the table at entry.
// The harness re-poison (855 MB fill) evicts the table from L3 every iteration;
// without the warm, the kernel opens with ~200k random 128B HBM reads under
// congestion. The warm streams the 25.6 MB table once, coalesced (~4 us), so
// the gather storm hits L3 instead of random HBM.
__global__ __launch_bounds__(256) void cond_filter_kernel(
    const int*   __restrict__ inp,     // (B, 51) int32
    const float* __restrict__ table,   // (100002, 64) fp32
    float*       __restrict__ out,     // (B, 3264) fp32
    int batch)
{
    // ---- L3 warm preamble (correctness-free; values sunk via asm) ----
    {
        const f4* t4 = (const f4*)table;
        const unsigned total  = TABLE_ROWS * 16u;          // 1,600,032 f4 elements
        const unsigned stride = gridDim.x * blockDim.x;    // 1,048,576 threads
        for (unsigned i = blockIdx.x * blockDim.x + threadIdx.x; i < total; i += stride) {
            f4 v = t4[i];
            asm volatile("" :: "v"(v.x), "v"(v.y), "v"(v.z), "v"(v.w));
        }
    }

    const int wave = threadIdx.x >> 6;            // 0..3
    const int lane = threadIdx.x & 63;
    int b = blockIdx.x * 4 + wave;
    b = __builtin_amdgcn_readfirstlane(b);        // prove wave-uniform -> s_loads
    if (b >= batch) return;

    const int grp = lane >> 4;                    // condition group 0..3
    const int gl  = lane & 15;                    // lane within group

    const int* row = inp + (size_t)b * ROW_STRIDE;
    const int e_idx = row[0];                     // scalar load

    // Per-iteration condition index: 4 scalar loads + 2-level cndmask select.
    int cidx[NITER];
    #pragma unroll
    for (int i = 0; i < NITER; ++i) {
        const int base = 1 + i * 4;
        const int s0 = row[base];
        const int s1 = (base + 1 < ROW_STRIDE) ? row[base + 1] : s0;
        const int s2 = (base + 2 < ROW_STRIDE) ? row[base + 2] : s0;
        const int s3 = (base + 3 < ROW_STRIDE) ? row[base + 3] : s0;
        cidx[i] = (grp & 1) ? ((grp & 2) ? s3 : s1)
                            : ((grp & 2) ? s2 : s0);
    }

    // Issue event gather + all 13 condition gathers back-to-back (max MLP).
    const f4 ev = *(const f4*)(table + (size_t)e_idx * EMB + gl * 4);
    f4 cv[NITER];
    #pragma unroll
    for (int i = 0; i < NITER; ++i)
        cv[i] = *(const f4*)(table + (size_t)cidx[i] * EMB + gl * 4);

    // Event norm (replicated across the 4 groups).
    const float es = reduce16(ev.x*ev.x + ev.y*ev.y + ev.z*ev.z + ev.w*ev.w);
    const float e_rn = rsqrtf(es);
    const f4 en = ev * e_rn;

    float* orow = out + (size_t)b * OUT_STRIDE;
    if (grp == 0) {
        // raw (un-normalized) event embedding, per reference; write-once -> nt
        __builtin_nontemporal_store(ev, (f4*)(orow + gl * 4));
    }

    #pragma unroll
    for (int i = 0; i < NITER; ++i) {
        const int c = i * 4 + grp;
        const f4 v = cv[i];
        const float cs = reduce16(v.x*v.x + v.y*v.y + v.z*v.z + v.w*v.w);
        const float dp = reduce16(v.x*en.x + v.y*en.y + v.z*en.z + v.w*en.w);
        // filtered = (v/|v|) * dot(en, v/|v|) = v * dp / cs
        const float scale = dp * __builtin_amdgcn_rcpf(cs);
        if (c < NCONDS) {
            const f4 o = v * scale;
            __builtin_nontemporal_store(o, (f4*)(orow + EMB + (size_t)c * EMB + gl * 4));
        }
    }
}

extern "C" void kernel_launch(void* const* d_in, const int* in_sizes, int n_in,
                              void* d_out, int out_size, void* d_ws, size_t ws_size,
                              hipStream_t stream) {
    const int*   inp   = (const int*)d_in[0];
    const float* table = (const float*)d_in[1];
    float*       out   = (float*)d_out;

    const int batch = in_sizes[0] / ROW_STRIDE;   // 16384
    const int blocks = (batch + 3) / 4;           // 4 rows per 256-thread block

    hipLaunchKernelGGL(cond_filter_kernel, dim3(blocks), dim3(256), 0, stream,
                       inp, table, out, batch);
}